// Round 13
// baseline (317.495 us; speedup 1.0000x reference)
//
#include <hip/hip_runtime.h>
#include <hip/hip_cooperative_groups.h>

namespace cg = cooperative_groups;

typedef float f4 __attribute__((ext_vector_type(4)));

#define HID 2048
#define DFF 5461
#define NE  8

// ws float offsets
#define WS_IS 0           // inv_s[8]
#define WS_T  64          // 8*2048 (normalized t)
#define WS_EO 16448       // 8*2048

// d_out used as large scratch (float offsets); fully overwritten by comb phase.
// Audit: TP [0, 1,048,576) | TS [1,048,576, 1,049,088) | MP [1,049,600, 1,748,608)
//        EP [1,748,736, 3,829,504)  -- disjoint, < 16,777,216
#define SC_TP 0
#define SC_TS 1048576
#define SC_MP 1049600
#define SC_EP 1748736

#define GRID_BLKS 512  // 2 blocks/CU; every phase sized to avoid spinning blocks

union SMem {
  struct { f4 dv4[64][2]; f4 red[3][NE][64]; } tp;   // 26,624 B
  struct { float red[8][32]; float sinv[NE]; } tr;
  struct { float t0[128]; float t1[128]; } mp;
  struct { float ml[4][43]; } eo;
  struct { float red[8][32]; } er;
  struct { float dvl[16][NE]; } cb;
};

// ================= fused cooperative kernel: 6 phases, R9 arithmetic =========
__global__ __launch_bounds__(256) void k_fused(
    const float* __restrict__ x, const float* __restrict__ rw,
    const float* __restrict__ up_w, const float* __restrict__ up_b,
    const float* __restrict__ down_w, const float* __restrict__ down_b,
    float* __restrict__ y, float* __restrict__ ws) {
  cg::grid_group grid = cg::this_grid();
  __shared__ SMem sm;
  int tid = threadIdx.x;
  float* sc = y;
  const int nb = gridDim.x;

  // ---- P1: t partials (512 vblocks: bxc = vb&7 col-block, rc = vb>>3) ----
  for (int vb = blockIdx.x; vb < 512; vb += nb) {
    int bxc = vb & 7, rc = vb >> 3;
    int col = tid & 63, rg = tid >> 6;
    int c4 = bxc * 64 + col;
    const f4* x4 = (const f4*)x;
    f4 acc[NE];
#pragma unroll
    for (int e = 0; e < NE; e++) acc[e] = (f4){0.f, 0.f, 0.f, 0.f};
    double spart = 0.0;
    for (int sub = 0; sub < 2; sub++) {
      int b0 = rc * 128 + sub * 64;
      if (tid < 128) {
        int row = tid >> 1, half = tid & 1;
        const float* rp = rw + (size_t)(b0 + row) * NE + half * 4;
        f4 d;
        d.x = __expf(rp[0]);
        d.y = __expf(rp[1]);
        d.z = __expf(rp[2]);
        d.w = __expf(rp[3]);
        sm.tp.dv4[row][half] = d;
      }
      __syncthreads();
      if (bxc == 0 && tid < NE) {
        const float* dp = (const float*)sm.tp.dv4;
        for (int row = 0; row < 64; row++) spart += (double)dp[row * 8 + tid];
      }
#pragma unroll 8
      for (int r = 0; r < 16; r++) {
        int row = rg * 16 + r;
        f4 xv = __builtin_nontemporal_load(&x4[(size_t)(b0 + row) * 512 + c4]);
        f4 dlo = sm.tp.dv4[row][0], dhi = sm.tp.dv4[row][1];
        acc[0] += dlo.x * xv;
        acc[1] += dlo.y * xv;
        acc[2] += dlo.z * xv;
        acc[3] += dlo.w * xv;
        acc[4] += dhi.x * xv;
        acc[5] += dhi.y * xv;
        acc[6] += dhi.z * xv;
        acc[7] += dhi.w * xv;
      }
      __syncthreads();
    }
    if (bxc == 0 && tid < NE) sc[SC_TS + rc * NE + tid] = (float)spart;
    if (rg) {
#pragma unroll
      for (int e = 0; e < NE; e++) sm.tp.red[rg - 1][e][col] = acc[e];
    }
    __syncthreads();
    if (!rg) {
      f4* o4 = (f4*)(sc + SC_TP);
#pragma unroll
      for (int e = 0; e < NE; e++) {
        f4 a = acc[e] + sm.tp.red[0][e][col] + sm.tp.red[1][e][col] +
               sm.tp.red[2][e][col];
        o4[(size_t)(rc * NE + e) * 512 + c4] = a;
      }
    }
    __syncthreads();
  }
  grid.sync();

  // ---- P2: t reduce + 1/s fold (512 vblocks) ----
  for (int vb = blockIdx.x; vb < 512; vb += nb) {
    if (tid < NE) {
      double s = 0.0;
      for (int ch = 0; ch < 64; ch++) s += (double)sc[SC_TS + ch * NE + tid];
      float inv = (float)(1.0 / s);
      sm.tr.sinv[tid] = inv;
      if (vb == 0) ws[WS_IS + tid] = inv;
    }
    int o = tid & 31, grp = tid >> 5;
    int i = vb * 32 + o;
    double a = 0.0;
#pragma unroll 4
    for (int k = 0; k < 8; k++)
      a += (double)sc[SC_TP + (size_t)(grp * 8 + k) * (NE * HID) + i];
    sm.tr.red[grp][o] = (float)a;
    __syncthreads();
    if (tid < 32) {
      int ii = vb * 32 + tid;
      float s = 0.f;
#pragma unroll
      for (int g = 0; g < 8; g++) s += sm.tr.red[g][tid];
      ws[WS_T + ii] = s * sm.tr.sinv[ii >> 11];
    }
    __syncthreads();
  }
  grid.sync();

  // ---- P3: up-proj partials (1024 vblocks: fb=vb&15 spans of 342,
  //          hc=(vb>>4)&15, g=vb>>8) -- exactly 2 rounds on 512 blocks ----
  for (int vb = blockIdx.x; vb < 1024; vb += nb) {
    int fb = vb & 15, hc = (vb >> 4) & 15, g = vb >> 8;
    int h0 = hc * 128;
    if (tid < 128) sm.mp.t0[tid] = ws[WS_T + (2 * g) * HID + h0 + tid];
    else sm.mp.t1[tid - 128] = ws[WS_T + (2 * g + 1) * HID + h0 + tid - 128];
    __syncthreads();
    int fstart = fb * 342;
    int fend = min(fstart + 342, DFF);
    int fA = fstart + tid;
    int fB = fA + 256;
    bool hasA = fA < fend, hasB = fB < fend;
    const float* wp = up_w + ((size_t)g * HID + h0) * DFF;
    float a0 = 0.f, a1 = 0.f, bb0 = 0.f, bb1 = 0.f;
#pragma unroll 16
    for (int h = 0; h < 128; h++) {
      float wA = hasA ? __builtin_nontemporal_load(wp + (size_t)h * DFF + fA) : 0.f;
      float wB = hasB ? __builtin_nontemporal_load(wp + (size_t)h * DFF + fB) : 0.f;
      a0 += sm.mp.t0[h] * wA;
      a1 += sm.mp.t1[h] * wA;
      bb0 += sm.mp.t0[h] * wB;
      bb1 += sm.mp.t1[h] * wB;
    }
    float* mp = sc + SC_MP + (size_t)hc * NE * DFF;
    if (hasA) {
      mp[(size_t)(2 * g) * DFF + fA] = a0;
      mp[(size_t)(2 * g + 1) * DFF + fA] = a1;
    }
    if (hasB) {
      mp[(size_t)(2 * g) * DFF + fB] = bb0;
      mp[(size_t)(2 * g + 1) * DFF + fB] = bb1;
    }
    __syncthreads();
  }
  grid.sync();

  // ---- P4: down-proj (2032 vblocks: hb=vb&1, fc=(vb>>1)%127, e=vb/254;
  //          3.97 rounds on 512 blocks) ----
  for (int vb = blockIdx.x; vb < 2032; vb += nb) {
    int hb = vb & 1, fc = (vb >> 1) % 127, e = vb / 254;
    int f0 = fc * 43;
    const f4* base4 =
        (const f4*)down_w + ((size_t)e * DFF + f0) * 512 + hb * 256 + tid;
    f4 w[8];
#pragma unroll
    for (int j = 0; j < 8; j++)
      w[j] = __builtin_nontemporal_load(&base4[(size_t)j * 512]);
    int lane = tid & 63, wv = tid >> 6;
    if (lane < 43) {
      double a = (double)up_b[(size_t)(e >> 1) * DFF + f0 + lane];
#pragma unroll 4
      for (int k = 0; k < 16; k++)
        a += (double)sc[SC_MP + (size_t)(k * NE + e) * DFF + f0 + lane];
      float af = (float)a;
      sm.eo.ml[wv][lane] = af / (1.f + __expf(-af));
    }
    f4 acc = (f4){0.f, 0.f, 0.f, 0.f};
    for (int blk = 0; blk < 5; blk++) {
#pragma unroll
      for (int j = 0; j < 8; j++) {
        int cur = blk * 8 + j;
        f4 c = w[j];
        int nxt = cur + 8;
        if (nxt < 43) w[j] = __builtin_nontemporal_load(&base4[(size_t)nxt * 512]);
        acc += sm.eo.ml[wv][cur] * c;
      }
    }
#pragma unroll
    for (int j = 0; j < 3; j++) acc += sm.eo.ml[wv][40 + j] * w[j];
    ((f4*)(sc + SC_EP))[(size_t)(fc * NE + e) * 512 + hb * 256 + tid] = acc;
    // ml is wave-local (indexed by wv): no block sync needed across iterations
  }
  grid.sync();

  // ---- P5: eo reduce + bias (512 vblocks) ----
  for (int vb = blockIdx.x; vb < 512; vb += nb) {
    int o = tid & 31, grp = tid >> 5;
    int i = vb * 32 + o;
    double a = 0.0;
    for (int fc = grp; fc < 127; fc += 8)
      a += (double)sc[SC_EP + (size_t)fc * (NE * HID) + i];
    sm.er.red[grp][o] = (float)a;
    __syncthreads();
    if (tid < 32) {
      int ii = vb * 32 + tid;
      float s = down_b[ii];
#pragma unroll
      for (int g = 0; g < 8; g++) s += sm.er.red[g][tid];
      ws[WS_EO + ii] = s;
    }
    __syncthreads();
  }
  grid.sync();

  // ---- P6: combine (512 vblocks, 16 tokens each) ----
  for (int vb = blockIdx.x; vb < 512; vb += nb) {
    int b0 = vb * 16;
    if (tid < 128) {
      int tok = tid >> 3, e = tid & 7;
      sm.cb.dvl[tok][e] = __expf(rw[(size_t)(b0 + tok) * NE + e]) * ws[WS_IS + e];
    }
    __syncthreads();
    const f4* eo4 = (const f4*)(ws + WS_EO);
    f4 ea[NE], eb[NE];
#pragma unroll
    for (int e = 0; e < NE; e++) {
      ea[e] = eo4[e * 512 + tid];
      eb[e] = eo4[e * 512 + 256 + tid];
    }
    f4* y4 = (f4*)y;
#pragma unroll 4
    for (int t = 0; t < 16; t++) {
      f4 o0 = (f4){0.f, 0.f, 0.f, 0.f};
      f4 o1 = (f4){0.f, 0.f, 0.f, 0.f};
#pragma unroll
      for (int e = 0; e < NE; e++) {
        float d = sm.cb.dvl[t][e];
        o0 += d * ea[e];
        o1 += d * eb[e];
      }
      __builtin_nontemporal_store(o0, &y4[(size_t)(b0 + t) * 512 + tid]);
      __builtin_nontemporal_store(o1, &y4[(size_t)(b0 + t) * 512 + 256 + tid]);
    }
    __syncthreads();
  }
}

// ================= fallback path: verified R9 six-kernel pipeline ============
__global__ __launch_bounds__(256) void k_tpart(const float* __restrict__ x,
                                               const float* __restrict__ rw,
                                               float* __restrict__ sc) {
  __shared__ f4 dv4[64][2];
  __shared__ f4 red[3][NE][64];
  int tid = threadIdx.x;
  int rc = blockIdx.y;
  int col = tid & 63, rg = tid >> 6;
  int c4 = blockIdx.x * 64 + col;
  const f4* x4 = (const f4*)x;
  f4 acc[NE];
#pragma unroll
  for (int e = 0; e < NE; e++) acc[e] = (f4){0.f, 0.f, 0.f, 0.f};
  double spart = 0.0;
  for (int sub = 0; sub < 2; sub++) {
    int b0 = rc * 128 + sub * 64;
    if (tid < 128) {
      int row = tid >> 1, half = tid & 1;
      const float* rp = rw + (size_t)(b0 + row) * NE + half * 4;
      f4 d;
      d.x = __expf(rp[0]);
      d.y = __expf(rp[1]);
      d.z = __expf(rp[2]);
      d.w = __expf(rp[3]);
      dv4[row][half] = d;
    }
    __syncthreads();
    if (blockIdx.x == 0 && tid < NE) {
      const float* dp = (const float*)dv4;
      for (int row = 0; row < 64; row++) spart += (double)dp[row * 8 + tid];
    }
#pragma unroll 8
    for (int r = 0; r < 16; r++) {
      int row = rg * 16 + r;
      f4 xv = __builtin_nontemporal_load(&x4[(size_t)(b0 + row) * 512 + c4]);
      f4 dlo = dv4[row][0], dhi = dv4[row][1];
      acc[0] += dlo.x * xv;
      acc[1] += dlo.y * xv;
      acc[2] += dlo.z * xv;
      acc[3] += dlo.w * xv;
      acc[4] += dhi.x * xv;
      acc[5] += dhi.y * xv;
      acc[6] += dhi.z * xv;
      acc[7] += dhi.w * xv;
    }
    __syncthreads();
  }
  if (blockIdx.x == 0 && tid < NE) sc[SC_TS + rc * NE + tid] = (float)spart;
  if (rg) {
#pragma unroll
    for (int e = 0; e < NE; e++) red[rg - 1][e][col] = acc[e];
  }
  __syncthreads();
  if (!rg) {
    f4* o4 = (f4*)(sc + SC_TP);
#pragma unroll
    for (int e = 0; e < NE; e++) {
      f4 a = acc[e] + red[0][e][col] + red[1][e][col] + red[2][e][col];
      o4[(size_t)(rc * NE + e) * 512 + c4] = a;
    }
  }
}

__global__ __launch_bounds__(256) void k_tred(const float* __restrict__ sc,
                                              float* __restrict__ ws) {
  __shared__ float red[8][32];
  __shared__ float sinv[NE];
  int tid = threadIdx.x;
  if (tid < NE) {
    double s = 0.0;
    for (int ch = 0; ch < 64; ch++) s += (double)sc[SC_TS + ch * NE + tid];
    float inv = (float)(1.0 / s);
    sinv[tid] = inv;
    if (blockIdx.x == 0) ws[WS_IS + tid] = inv;
  }
  int o = tid & 31, grp = tid >> 5;
  int i = blockIdx.x * 32 + o;
  double a = 0.0;
#pragma unroll 4
  for (int k = 0; k < 8; k++)
    a += (double)sc[SC_TP + (size_t)(grp * 8 + k) * (NE * HID) + i];
  red[grp][o] = (float)a;
  __syncthreads();
  if (tid < 32) {
    int ii = blockIdx.x * 32 + tid;
    float s = 0.f;
#pragma unroll
    for (int g = 0; g < 8; g++) s += red[g][tid];
    ws[WS_T + ii] = s * sinv[ii >> 11];
  }
}

__global__ __launch_bounds__(256) void k_midpart(const float* __restrict__ up_w,
                                                 const float* __restrict__ ws,
                                                 float* __restrict__ sc) {
  int fb = blockIdx.x, hc = blockIdx.y, g = blockIdx.z;
  int tid = threadIdx.x;
  __shared__ float t0[128], t1[128];
  int h0 = hc * 128;
  if (tid < 128) t0[tid] = ws[WS_T + (2 * g) * HID + h0 + tid];
  else t1[tid - 128] = ws[WS_T + (2 * g + 1) * HID + h0 + tid - 128];
  __syncthreads();
  int fA = fb * 512 + tid;
  int fB = fA + 256;
  bool hasB = fB < DFF;
  const float* wp = up_w + ((size_t)g * HID + h0) * DFF;
  float a0 = 0.f, a1 = 0.f, bb0 = 0.f, bb1 = 0.f;
#pragma unroll 8
  for (int h = 0; h < 128; h++) {
    float wA = __builtin_nontemporal_load(wp + (size_t)h * DFF + fA);
    float wB = hasB ? __builtin_nontemporal_load(wp + (size_t)h * DFF + fB) : 0.f;
    a0 += t0[h] * wA;
    a1 += t1[h] * wA;
    bb0 += t0[h] * wB;
    bb1 += t1[h] * wB;
  }
  float* mp = sc + SC_MP + (size_t)hc * NE * DFF;
  mp[(size_t)(2 * g) * DFF + fA] = a0;
  mp[(size_t)(2 * g + 1) * DFF + fA] = a1;
  if (hasB) {
    mp[(size_t)(2 * g) * DFF + fB] = bb0;
    mp[(size_t)(2 * g + 1) * DFF + fB] = bb1;
  }
}

__global__ __launch_bounds__(256) void k_eopart(const float* __restrict__ down_w,
                                                const float* __restrict__ up_b,
                                                const float* __restrict__ sc_mp,
                                                float* __restrict__ sc) {
  int hb = blockIdx.x, fc = blockIdx.y, e = blockIdx.z;
  int tid = threadIdx.x;
  int f0 = fc * 43;
  const f4* base4 = (const f4*)down_w + ((size_t)e * DFF + f0) * 512 + hb * 256 + tid;
  f4 w[8];
#pragma unroll
  for (int j = 0; j < 8; j++)
    w[j] = __builtin_nontemporal_load(&base4[(size_t)j * 512]);
  __shared__ float ml[4][43];
  int lane = tid & 63, wv = tid >> 6;
  if (lane < 43) {
    double a = (double)up_b[(size_t)(e >> 1) * DFF + f0 + lane];
#pragma unroll 4
    for (int k = 0; k < 16; k++)
      a += (double)sc_mp[SC_MP + (size_t)(k * NE + e) * DFF + f0 + lane];
    float af = (float)a;
    ml[wv][lane] = af / (1.f + __expf(-af));
  }
  f4 acc = (f4){0.f, 0.f, 0.f, 0.f};
  for (int blk = 0; blk < 5; blk++) {
#pragma unroll
    for (int j = 0; j < 8; j++) {
      int cur = blk * 8 + j;
      f4 c = w[j];
      int nxt = cur + 8;
      if (nxt < 43) w[j] = __builtin_nontemporal_load(&base4[(size_t)nxt * 512]);
      acc += ml[wv][cur] * c;
    }
  }
#pragma unroll
  for (int j = 0; j < 3; j++) acc += ml[wv][40 + j] * w[j];
  ((f4*)(sc + SC_EP))[(size_t)(fc * NE + e) * 512 + hb * 256 + tid] = acc;
}

__global__ __launch_bounds__(256) void k_eored(const float* __restrict__ sc,
                                               const float* __restrict__ down_b,
                                               float* __restrict__ ws) {
  __shared__ float red[8][32];
  int tid = threadIdx.x;
  int o = tid & 31, grp = tid >> 5;
  int i = blockIdx.x * 32 + o;
  double a = 0.0;
  for (int fc = grp; fc < 127; fc += 8)
    a += (double)sc[SC_EP + (size_t)fc * (NE * HID) + i];
  red[grp][o] = (float)a;
  __syncthreads();
  if (tid < 32) {
    int ii = blockIdx.x * 32 + tid;
    float s = down_b[ii];
#pragma unroll
    for (int g = 0; g < 8; g++) s += red[g][tid];
    ws[WS_EO + ii] = s;
  }
}

__global__ __launch_bounds__(256) void k_comb(const float* __restrict__ rw,
                                              const float* __restrict__ ws,
                                              float* __restrict__ y) {
  int tid = threadIdx.x;
  int b0 = blockIdx.x * 16;
  __shared__ float dvl[16][NE];
  if (tid < 128) {
    int tok = tid >> 3, e = tid & 7;
    dvl[tok][e] = __expf(rw[(size_t)(b0 + tok) * NE + e]) * ws[WS_IS + e];
  }
  __syncthreads();
  const f4* eo4 = (const f4*)(ws + WS_EO);
  f4 ea[NE], eb[NE];
#pragma unroll
  for (int e = 0; e < NE; e++) {
    ea[e] = eo4[e * 512 + tid];
    eb[e] = eo4[e * 512 + 256 + tid];
  }
  f4* y4 = (f4*)y;
#pragma unroll 4
  for (int t = 0; t < 16; t++) {
    f4 o0 = (f4){0.f, 0.f, 0.f, 0.f};
    f4 o1 = (f4){0.f, 0.f, 0.f, 0.f};
#pragma unroll
    for (int e = 0; e < NE; e++) {
      float d = dvl[t][e];
      o0 += d * ea[e];
      o1 += d * eb[e];
    }
    __builtin_nontemporal_store(o0, &y4[(size_t)(b0 + t) * 512 + tid]);
    __builtin_nontemporal_store(o1, &y4[(size_t)(b0 + t) * 512 + 256 + tid]);
  }
}

extern "C" void kernel_launch(void* const* d_in, const int* in_sizes, int n_in,
                              void* d_out, int out_size, void* d_ws, size_t ws_size,
                              hipStream_t stream) {
  const float* x      = (const float*)d_in[0];
  const float* rw     = (const float*)d_in[1];
  const float* up_w   = (const float*)d_in[2];
  const float* up_b   = (const float*)d_in[3];
  const float* down_w = (const float*)d_in[4];
  const float* down_b = (const float*)d_in[5];
  float* y  = (float*)d_out;
  float* ws = (float*)d_ws;
  float* sc = y;

  // fixed 2-blocks/CU grid; validate co-residency against the occupancy query
  int maxB = 0;
  hipError_t qerr =
      hipOccupancyMaxActiveBlocksPerMultiprocessor(&maxB, k_fused, 256, 0);
  int grid = GRID_BLKS;
  if (qerr != hipSuccess || maxB < 1) grid = 0;
  else if (maxB * 256 < grid) grid = maxB * 256;

  hipError_t lerr = hipErrorUnknown;
  if (grid > 0) {
    void* args[] = {(void*)&x, (void*)&rw, (void*)&up_w, (void*)&up_b,
                    (void*)&down_w, (void*)&down_b, (void*)&y, (void*)&ws};
    lerr = hipLaunchCooperativeKernel((const void*)k_fused, dim3(grid),
                                      dim3(256), args, 0, stream);
  }
  if (lerr != hipSuccess) {
    // fallback: verified R9 six-kernel pipeline (~132 us)
    hipLaunchKernelGGL(k_tpart, dim3(8, 64), dim3(256), 0, stream, x, rw, sc);
    hipLaunchKernelGGL(k_tred, dim3(512), dim3(256), 0, stream, sc, ws);
    hipLaunchKernelGGL(k_midpart, dim3(11, 16, 4), dim3(256), 0, stream, up_w, ws, sc);
    hipLaunchKernelGGL(k_eopart, dim3(2, 127, 8), dim3(256), 0, stream, down_w, up_b, sc, sc);
    hipLaunchKernelGGL(k_eored, dim3(512), dim3(256), 0, stream, sc, down_b, ws);
    hipLaunchKernelGGL(k_comb, dim3(512), dim3(256), 0, stream, rw, ws, y);
  }
}

// Round 14
// 137.978 us; speedup vs baseline: 2.3010x; 2.3010x over previous
//
#include <hip/hip_runtime.h>

typedef float f4 __attribute__((ext_vector_type(4)));

#define HID 2048
#define DFF 5461
#define NE  8

// ws float offsets
#define WS_IS 0           // inv_s[8]
#define WS_T  64          // 8*2048 (normalized t)
#define WS_EO 16448       // 8*2048

// d_out used as large scratch (float offsets); fully overwritten by k_comb.
// Audit: TP [0, 1,048,576) | TS [1,048,576, 1,049,088) | MP [1,049,600, 1,748,608)
//        EP [1,748,736, 3,829,504)  -- disjoint, < 16,777,216
#define SC_TP 0
#define SC_TS 1048576
#define SC_MP 1049600
#define SC_EP 1748736

// ---- t partials (unnormalized exp weights; s partials in double):
// grid (8 col-blocks of 64 f4, 64 row-chunks of 128), block 256
__global__ __launch_bounds__(256) void k_tpart(const float* __restrict__ x,
                                               const float* __restrict__ rw,
                                               float* __restrict__ sc) {
  __shared__ f4 dv4[64][2];
  __shared__ f4 red[3][NE][64];
  int tid = threadIdx.x;
  int rc = blockIdx.y;
  int col = tid & 63, rg = tid >> 6;
  int c4 = blockIdx.x * 64 + col;
  const f4* x4 = (const f4*)x;
  f4 acc[NE];
#pragma unroll
  for (int e = 0; e < NE; e++) acc[e] = (f4){0.f, 0.f, 0.f, 0.f};
  double spart = 0.0;
  for (int sub = 0; sub < 2; sub++) {
    int b0 = rc * 128 + sub * 64;
    if (tid < 128) {
      int row = tid >> 1, half = tid & 1;
      const float* rp = rw + (size_t)(b0 + row) * NE + half * 4;
      f4 d;
      d.x = __expf(rp[0]);
      d.y = __expf(rp[1]);
      d.z = __expf(rp[2]);
      d.w = __expf(rp[3]);
      dv4[row][half] = d;
    }
    __syncthreads();
    // exp-sum chunk partials (only col-block 0; threads 0..7) -- DOUBLE accum
    if (blockIdx.x == 0 && tid < NE) {
      const float* dp = (const float*)dv4;
      for (int row = 0; row < 64; row++) spart += (double)dp[row * 8 + tid];
    }
#pragma unroll 8
    for (int r = 0; r < 16; r++) {
      int row = rg * 16 + r;
      f4 xv = __builtin_nontemporal_load(&x4[(size_t)(b0 + row) * 512 + c4]);
      f4 dlo = dv4[row][0], dhi = dv4[row][1];
      acc[0] += dlo.x * xv;
      acc[1] += dlo.y * xv;
      acc[2] += dlo.z * xv;
      acc[3] += dlo.w * xv;
      acc[4] += dhi.x * xv;
      acc[5] += dhi.y * xv;
      acc[6] += dhi.z * xv;
      acc[7] += dhi.w * xv;
    }
    __syncthreads();
  }
  if (blockIdx.x == 0 && tid < NE) sc[SC_TS + rc * NE + tid] = (float)spart;
  if (rg) {
#pragma unroll
    for (int e = 0; e < NE; e++) red[rg - 1][e][col] = acc[e];
  }
  __syncthreads();
  if (!rg) {
    f4* o4 = (f4*)(sc + SC_TP);
#pragma unroll
    for (int e = 0; e < NE; e++) {
      f4 a = acc[e] + red[0][e][col] + red[1][e][col] + red[2][e][col];
      o4[(size_t)(rc * NE + e) * 512 + c4] = a;
    }
  }
}

// ---- t reduce + 1/s fold: 512 blocks, 32 outputs each, 8 chunk-groups of 8
__global__ __launch_bounds__(256) void k_tred(const float* __restrict__ sc,
                                              float* __restrict__ ws) {
  __shared__ float red[8][32];
  __shared__ float sinv[NE];
  int tid = threadIdx.x;
  if (tid < NE) {
    double s = 0.0;  // DOUBLE accum over 64 chunk partials
    for (int ch = 0; ch < 64; ch++) s += (double)sc[SC_TS + ch * NE + tid];
    float inv = (float)(1.0 / s);
    sinv[tid] = inv;
    if (blockIdx.x == 0) ws[WS_IS + tid] = inv;
  }
  int o = tid & 31, grp = tid >> 5;
  int i = blockIdx.x * 32 + o;
  double a = 0.0;
#pragma unroll 4
  for (int k = 0; k < 8; k++)
    a += (double)sc[SC_TP + (size_t)(grp * 8 + k) * (NE * HID) + i];
  red[grp][o] = (float)a;
  __syncthreads();
  if (tid < 32) {
    int ii = blockIdx.x * 32 + tid;
    float s = 0.f;
#pragma unroll
    for (int g = 0; g < 8; g++) s += red[g][tid];
    ws[WS_T + ii] = s * sinv[ii >> 11];
  }
}

// ---- up-proj partials: grid (16 f-spans of 342, 16 h-chunks of 128, 4 groups)
// = 1024 blocks, 4.0/CU exact; t from ws (tiny, cached)
__global__ __launch_bounds__(256) void k_midpart(const float* __restrict__ up_w,
                                                 const float* __restrict__ ws,
                                                 float* __restrict__ sc) {
  int fb = blockIdx.x, hc = blockIdx.y, g = blockIdx.z;
  int tid = threadIdx.x;
  __shared__ float t0[128], t1[128];
  int h0 = hc * 128;
  if (tid < 128) t0[tid] = ws[WS_T + (2 * g) * HID + h0 + tid];
  else t1[tid - 128] = ws[WS_T + (2 * g + 1) * HID + h0 + tid - 128];
  __syncthreads();
  int fstart = fb * 342;
  int fend = min(fstart + 342, DFF);
  int fA = fstart + tid;
  int fB = fA + 256;
  bool hasA = fA < fend, hasB = fB < fend;
  const float* wp = up_w + ((size_t)g * HID + h0) * DFF;
  float a0 = 0.f, a1 = 0.f, bb0 = 0.f, bb1 = 0.f;
#pragma unroll 8
  for (int h = 0; h < 128; h++) {
    float wA = hasA ? __builtin_nontemporal_load(wp + (size_t)h * DFF + fA) : 0.f;
    float wB = hasB ? __builtin_nontemporal_load(wp + (size_t)h * DFF + fB) : 0.f;
    a0 += t0[h] * wA;
    a1 += t1[h] * wA;
    bb0 += t0[h] * wB;
    bb1 += t1[h] * wB;
  }
  float* mp = sc + SC_MP + (size_t)hc * NE * DFF;
  if (hasA) {
    mp[(size_t)(2 * g) * DFF + fA] = a0;
    mp[(size_t)(2 * g + 1) * DFF + fA] = a1;
  }
  if (hasB) {
    mp[(size_t)(2 * g) * DFF + fB] = bb0;
    mp[(size_t)(2 * g + 1) * DFF + fB] = bb1;
  }
}

// ---- down-proj: grid (2 h-halves, 127 f-chunks of 43, 8 experts), block 256
// fused mid reduce (double) + bias + silu, wave-local; 8-row preload pipeline
__global__ __launch_bounds__(256) void k_eopart(const float* __restrict__ down_w,
                                                const float* __restrict__ up_b,
                                                const float* __restrict__ sc_mp,
                                                float* __restrict__ sc) {
  int hb = blockIdx.x, fc = blockIdx.y, e = blockIdx.z;
  int tid = threadIdx.x;
  int f0 = fc * 43;
  const f4* base4 = (const f4*)down_w + ((size_t)e * DFF + f0) * 512 + hb * 256 + tid;
  // preload first 8 rows (in flight across the prologue)
  f4 w[8];
#pragma unroll
  for (int j = 0; j < 8; j++)
    w[j] = __builtin_nontemporal_load(&base4[(size_t)j * 512]);
  // wave-local mid finalize: 16-chunk reduce (double) + bias + silu
  __shared__ float ml[4][43];
  int lane = tid & 63, wv = tid >> 6;
  if (lane < 43) {
    double a = (double)up_b[(size_t)(e >> 1) * DFF + f0 + lane];
#pragma unroll 4
    for (int k = 0; k < 16; k++)
      a += (double)sc_mp[SC_MP + (size_t)(k * NE + e) * DFF + f0 + lane];
    float af = (float)a;
    ml[wv][lane] = af / (1.f + __expf(-af));
  }
  f4 acc = (f4){0.f, 0.f, 0.f, 0.f};
  for (int blk = 0; blk < 5; blk++) {
#pragma unroll
    for (int j = 0; j < 8; j++) {
      int cur = blk * 8 + j;
      f4 c = w[j];
      int nxt = cur + 8;
      if (nxt < 43) w[j] = __builtin_nontemporal_load(&base4[(size_t)nxt * 512]);
      acc += ml[wv][cur] * c;
    }
  }
#pragma unroll
  for (int j = 0; j < 3; j++) acc += ml[wv][40 + j] * w[j];
  ((f4*)(sc + SC_EP))[(size_t)(fc * NE + e) * 512 + hb * 256 + tid] = acc;
}

// ---- eo reduce + bias: 512 blocks, 32 outputs each (double inner)
__global__ __launch_bounds__(256) void k_eored(const float* __restrict__ sc,
                                               const float* __restrict__ down_b,
                                               float* __restrict__ ws) {
  __shared__ float red[8][32];
  int tid = threadIdx.x;
  int o = tid & 31, grp = tid >> 5;
  int i = blockIdx.x * 32 + o;
  double a = 0.0;
  for (int fc = grp; fc < 127; fc += 8)
    a += (double)sc[SC_EP + (size_t)fc * (NE * HID) + i];
  red[grp][o] = (float)a;
  __syncthreads();
  if (tid < 32) {
    int ii = blockIdx.x * 32 + tid;
    float s = down_b[ii];
#pragma unroll
    for (int g = 0; g < 8; g++) s += red[g][tid];
    ws[WS_EO + ii] = s;
  }
}

// ---- combine: 1024 blocks x 8 tokens, eo in regs, nt stores
__global__ __launch_bounds__(256) void k_comb(const float* __restrict__ rw,
                                              const float* __restrict__ ws,
                                              float* __restrict__ y) {
  int tid = threadIdx.x;
  int b0 = blockIdx.x * 8;
  __shared__ float dvl[8][NE];
  if (tid < 64) {
    int tok = tid >> 3, e = tid & 7;
    dvl[tok][e] = __expf(rw[(size_t)(b0 + tok) * NE + e]) * ws[WS_IS + e];
  }
  __syncthreads();
  const f4* eo4 = (const f4*)(ws + WS_EO);
  f4 ea[NE], eb[NE];
#pragma unroll
  for (int e = 0; e < NE; e++) {
    ea[e] = eo4[e * 512 + tid];
    eb[e] = eo4[e * 512 + 256 + tid];
  }
  f4* y4 = (f4*)y;
#pragma unroll 4
  for (int t = 0; t < 8; t++) {
    f4 o0 = (f4){0.f, 0.f, 0.f, 0.f};
    f4 o1 = (f4){0.f, 0.f, 0.f, 0.f};
#pragma unroll
    for (int e = 0; e < NE; e++) {
      float d = dvl[t][e];
      o0 += d * ea[e];
      o1 += d * eb[e];
    }
    __builtin_nontemporal_store(o0, &y4[(size_t)(b0 + t) * 512 + tid]);
    __builtin_nontemporal_store(o1, &y4[(size_t)(b0 + t) * 512 + 256 + tid]);
  }
}

extern "C" void kernel_launch(void* const* d_in, const int* in_sizes, int n_in,
                              void* d_out, int out_size, void* d_ws, size_t ws_size,
                              hipStream_t stream) {
  const float* x      = (const float*)d_in[0];
  const float* rw     = (const float*)d_in[1];
  const float* up_w   = (const float*)d_in[2];
  const float* up_b   = (const float*)d_in[3];
  const float* down_w = (const float*)d_in[4];
  const float* down_b = (const float*)d_in[5];
  float* y  = (float*)d_out;
  float* ws = (float*)d_ws;
  float* sc = y;  // large scratch in d_out; k_comb overwrites all of it

  hipLaunchKernelGGL(k_tpart, dim3(8, 64), dim3(256), 0, stream, x, rw, sc);
  hipLaunchKernelGGL(k_tred, dim3(512), dim3(256), 0, stream, sc, ws);
  hipLaunchKernelGGL(k_midpart, dim3(16, 16, 4), dim3(256), 0, stream, up_w, ws, sc);
  hipLaunchKernelGGL(k_eopart, dim3(2, 127, 8), dim3(256), 0, stream, down_w, up_b, sc, sc);
  hipLaunchKernelGGL(k_eored, dim3(512), dim3(256), 0, stream, sc, down_b, ws);
  hipLaunchKernelGGL(k_comb, dim3(1024), dim3(256), 0, stream, rw, ws, y);
}

// Round 15
// 133.509 us; speedup vs baseline: 2.3781x; 1.0335x over previous
//
#include <hip/hip_runtime.h>

typedef float f4 __attribute__((ext_vector_type(4)));

#define HID 2048
#define DFF 5461
#define NE  8

// ws float offsets
#define WS_IS 0           // inv_s[8]
#define WS_T  64          // 8*2048 (normalized t)
#define WS_EO 16448       // 8*2048

// d_out used as large scratch (float offsets); fully overwritten by k_comb.
// Audit: TP [0, 1,048,576) | TS [1,048,576, 1,049,088) | MP [1,049,600, 1,748,608)
//        EP [1,748,736, 3,829,504)  -- disjoint, < 16,777,216
#define SC_TP 0
#define SC_TS 1048576
#define SC_MP 1049600
#define SC_EP 1748736

// ---- t partials (unnormalized exp weights; s partials in double):
// grid (8 col-blocks of 64 f4, 64 row-chunks of 128), block 256
__global__ __launch_bounds__(256) void k_tpart(const float* __restrict__ x,
                                               const float* __restrict__ rw,
                                               float* __restrict__ sc) {
  __shared__ f4 dv4[64][2];
  __shared__ f4 red[3][NE][64];
  int tid = threadIdx.x;
  int rc = blockIdx.y;
  int col = tid & 63, rg = tid >> 6;
  int c4 = blockIdx.x * 64 + col;
  const f4* x4 = (const f4*)x;
  f4 acc[NE];
#pragma unroll
  for (int e = 0; e < NE; e++) acc[e] = (f4){0.f, 0.f, 0.f, 0.f};
  double spart = 0.0;
  for (int sub = 0; sub < 2; sub++) {
    int b0 = rc * 128 + sub * 64;
    if (tid < 128) {
      int row = tid >> 1, half = tid & 1;
      const float* rp = rw + (size_t)(b0 + row) * NE + half * 4;
      f4 d;
      d.x = __expf(rp[0]);
      d.y = __expf(rp[1]);
      d.z = __expf(rp[2]);
      d.w = __expf(rp[3]);
      dv4[row][half] = d;
    }
    __syncthreads();
    // exp-sum chunk partials (only col-block 0; threads 0..7) -- DOUBLE accum
    if (blockIdx.x == 0 && tid < NE) {
      const float* dp = (const float*)dv4;
      for (int row = 0; row < 64; row++) spart += (double)dp[row * 8 + tid];
    }
#pragma unroll 8
    for (int r = 0; r < 16; r++) {
      int row = rg * 16 + r;
      f4 xv = __builtin_nontemporal_load(&x4[(size_t)(b0 + row) * 512 + c4]);
      f4 dlo = dv4[row][0], dhi = dv4[row][1];
      acc[0] += dlo.x * xv;
      acc[1] += dlo.y * xv;
      acc[2] += dlo.z * xv;
      acc[3] += dlo.w * xv;
      acc[4] += dhi.x * xv;
      acc[5] += dhi.y * xv;
      acc[6] += dhi.z * xv;
      acc[7] += dhi.w * xv;
    }
    __syncthreads();
  }
  if (blockIdx.x == 0 && tid < NE) sc[SC_TS + rc * NE + tid] = (float)spart;
  if (rg) {
#pragma unroll
    for (int e = 0; e < NE; e++) red[rg - 1][e][col] = acc[e];
  }
  __syncthreads();
  if (!rg) {
    f4* o4 = (f4*)(sc + SC_TP);
#pragma unroll
    for (int e = 0; e < NE; e++) {
      f4 a = acc[e] + red[0][e][col] + red[1][e][col] + red[2][e][col];
      o4[(size_t)(rc * NE + e) * 512 + c4] = a;
    }
  }
}

// ---- t reduce + 1/s fold: 512 blocks, 32 outputs each, 8 chunk-groups of 8
__global__ __launch_bounds__(256) void k_tred(const float* __restrict__ sc,
                                              float* __restrict__ ws) {
  __shared__ float red[8][32];
  __shared__ float sinv[NE];
  int tid = threadIdx.x;
  if (tid < NE) {
    double s = 0.0;  // DOUBLE accum over 64 chunk partials
    for (int ch = 0; ch < 64; ch++) s += (double)sc[SC_TS + ch * NE + tid];
    float inv = (float)(1.0 / s);
    sinv[tid] = inv;
    if (blockIdx.x == 0) ws[WS_IS + tid] = inv;
  }
  int o = tid & 31, grp = tid >> 5;
  int i = blockIdx.x * 32 + o;
  double a = 0.0;
#pragma unroll 4
  for (int k = 0; k < 8; k++)
    a += (double)sc[SC_TP + (size_t)(grp * 8 + k) * (NE * HID) + i];
  red[grp][o] = (float)a;
  __syncthreads();
  if (tid < 32) {
    int ii = blockIdx.x * 32 + tid;
    float s = 0.f;
#pragma unroll
    for (int g = 0; g < 8; g++) s += red[g][tid];
    ws[WS_T + ii] = s * sinv[ii >> 11];
  }
}

// ---- up-proj partials: grid (11 f-spans of 512, 16 h-chunks of 128, 4 groups)
__global__ __launch_bounds__(256) void k_midpart(const float* __restrict__ up_w,
                                                 const float* __restrict__ ws,
                                                 float* __restrict__ sc) {
  int fb = blockIdx.x, hc = blockIdx.y, g = blockIdx.z;
  int tid = threadIdx.x;
  __shared__ float t0[128], t1[128];
  int h0 = hc * 128;
  if (tid < 128) t0[tid] = ws[WS_T + (2 * g) * HID + h0 + tid];
  else t1[tid - 128] = ws[WS_T + (2 * g + 1) * HID + h0 + tid - 128];
  __syncthreads();
  int fA = fb * 512 + tid;  // < 5376 always
  int fB = fA + 256;
  bool hasB = fB < DFF;
  const float* wp = up_w + ((size_t)g * HID + h0) * DFF;
  float a0 = 0.f, a1 = 0.f, bb0 = 0.f, bb1 = 0.f;
#pragma unroll 8
  for (int h = 0; h < 128; h++) {
    float wA = __builtin_nontemporal_load(wp + (size_t)h * DFF + fA);
    float wB = hasB ? __builtin_nontemporal_load(wp + (size_t)h * DFF + fB) : 0.f;
    a0 += t0[h] * wA;
    a1 += t1[h] * wA;
    bb0 += t0[h] * wB;
    bb1 += t1[h] * wB;
  }
  float* mp = sc + SC_MP + (size_t)hc * NE * DFF;
  mp[(size_t)(2 * g) * DFF + fA] = a0;
  mp[(size_t)(2 * g + 1) * DFF + fA] = a1;
  if (hasB) {
    mp[(size_t)(2 * g) * DFF + fB] = bb0;
    mp[(size_t)(2 * g + 1) * DFF + fB] = bb1;
  }
}

// ---- down-proj: grid (2 h-halves, 127 f-chunks of 43, 8 experts), block 256
// fused mid reduce (double) + bias + silu, wave-local; 8-row preload pipeline
__global__ __launch_bounds__(256) void k_eopart(const float* __restrict__ down_w,
                                                const float* __restrict__ up_b,
                                                const float* __restrict__ sc_mp,
                                                float* __restrict__ sc) {
  int hb = blockIdx.x, fc = blockIdx.y, e = blockIdx.z;
  int tid = threadIdx.x;
  int f0 = fc * 43;
  const f4* base4 = (const f4*)down_w + ((size_t)e * DFF + f0) * 512 + hb * 256 + tid;
  // preload first 8 rows (in flight across the prologue)
  f4 w[8];
#pragma unroll
  for (int j = 0; j < 8; j++)
    w[j] = __builtin_nontemporal_load(&base4[(size_t)j * 512]);
  // wave-local mid finalize: 16-chunk reduce (double) + bias + silu
  __shared__ float ml[4][43];
  int lane = tid & 63, wv = tid >> 6;
  if (lane < 43) {
    double a = (double)up_b[(size_t)(e >> 1) * DFF + f0 + lane];
#pragma unroll 4
    for (int k = 0; k < 16; k++)
      a += (double)sc_mp[SC_MP + (size_t)(k * NE + e) * DFF + f0 + lane];
    float af = (float)a;
    ml[wv][lane] = af / (1.f + __expf(-af));
  }
  f4 acc = (f4){0.f, 0.f, 0.f, 0.f};
  for (int blk = 0; blk < 5; blk++) {
#pragma unroll
    for (int j = 0; j < 8; j++) {
      int cur = blk * 8 + j;
      f4 c = w[j];
      int nxt = cur + 8;
      if (nxt < 43) w[j] = __builtin_nontemporal_load(&base4[(size_t)nxt * 512]);
      acc += ml[wv][cur] * c;
    }
  }
#pragma unroll
  for (int j = 0; j < 3; j++) acc += ml[wv][40 + j] * w[j];
  ((f4*)(sc + SC_EP))[(size_t)(fc * NE + e) * 512 + hb * 256 + tid] = acc;
}

// ---- eo reduce + bias: 512 blocks, 32 outputs each (double inner)
__global__ __launch_bounds__(256) void k_eored(const float* __restrict__ sc,
                                               const float* __restrict__ down_b,
                                               float* __restrict__ ws) {
  __shared__ float red[8][32];
  int tid = threadIdx.x;
  int o = tid & 31, grp = tid >> 5;
  int i = blockIdx.x * 32 + o;
  double a = 0.0;
  for (int fc = grp; fc < 127; fc += 8)
    a += (double)sc[SC_EP + (size_t)fc * (NE * HID) + i];
  red[grp][o] = (float)a;
  __syncthreads();
  if (tid < 32) {
    int ii = blockIdx.x * 32 + tid;
    float s = down_b[ii];
#pragma unroll
    for (int g = 0; g < 8; g++) s += red[g][tid];
    ws[WS_EO + ii] = s;
  }
}

// ---- combine: 16 tokens/block, eo in regs, nt stores
__global__ __launch_bounds__(256) void k_comb(const float* __restrict__ rw,
                                              const float* __restrict__ ws,
                                              float* __restrict__ y) {
  int tid = threadIdx.x;
  int b0 = blockIdx.x * 16;
  __shared__ float dvl[16][NE];
  if (tid < 128) {
    int tok = tid >> 3, e = tid & 7;
    dvl[tok][e] = __expf(rw[(size_t)(b0 + tok) * NE + e]) * ws[WS_IS + e];
  }
  __syncthreads();
  const f4* eo4 = (const f4*)(ws + WS_EO);
  f4 ea[NE], eb[NE];
#pragma unroll
  for (int e = 0; e < NE; e++) {
    ea[e] = eo4[e * 512 + tid];
    eb[e] = eo4[e * 512 + 256 + tid];
  }
  f4* y4 = (f4*)y;
#pragma unroll 4
  for (int t = 0; t < 16; t++) {
    f4 o0 = (f4){0.f, 0.f, 0.f, 0.f};
    f4 o1 = (f4){0.f, 0.f, 0.f, 0.f};
#pragma unroll
    for (int e = 0; e < NE; e++) {
      float d = dvl[t][e];
      o0 += d * ea[e];
      o1 += d * eb[e];
    }
    __builtin_nontemporal_store(o0, &y4[(size_t)(b0 + t) * 512 + tid]);
    __builtin_nontemporal_store(o1, &y4[(size_t)(b0 + t) * 512 + 256 + tid]);
  }
}

extern "C" void kernel_launch(void* const* d_in, const int* in_sizes, int n_in,
                              void* d_out, int out_size, void* d_ws, size_t ws_size,
                              hipStream_t stream) {
  const float* x      = (const float*)d_in[0];
  const float* rw     = (const float*)d_in[1];
  const float* up_w   = (const float*)d_in[2];
  const float* up_b   = (const float*)d_in[3];
  const float* down_w = (const float*)d_in[4];
  const float* down_b = (const float*)d_in[5];
  float* y  = (float*)d_out;
  float* ws = (float*)d_ws;
  float* sc = y;  // large scratch in d_out; k_comb overwrites all of it

  hipLaunchKernelGGL(k_tpart, dim3(8, 64), dim3(256), 0, stream, x, rw, sc);
  hipLaunchKernelGGL(k_tred, dim3(512), dim3(256), 0, stream, sc, ws);
  hipLaunchKernelGGL(k_midpart, dim3(11, 16, 4), dim3(256), 0, stream, up_w, ws, sc);
  hipLaunchKernelGGL(k_eopart, dim3(2, 127, 8), dim3(256), 0, stream, down_w, up_b, sc, sc);
  hipLaunchKernelGGL(k_eored, dim3(512), dim3(256), 0, stream, sc, down_b, ws);
  hipLaunchKernelGGL(k_comb, dim3(512), dim3(256), 0, stream, rw, ws, y);
}